// Round 5
// baseline (373.778 us; speedup 1.0000x reference)
//
#include <hip/hip_runtime.h>

// Problem constants
#define BB   4
#define CC   128
#define DHW  32768           // 32*32*32
#define NN   131072          // BB*DHW
#define KK   1024

// Output layout (floats, concatenated in reference return order)
#define OUT_Q    0
#define OUT_LOSS 16777216
#define OUT_IDX  16777217
#define OUT_ESUM 16908289
#define OUT_EMB  16908545

// Workspace layout (float offsets). Total ~2.1 MB.
#define WS_EMBT  0           // 131072 floats: embT[c][k]  (for quant gather)
#define WS_ENH   131072      // 1024 floats: 0.5*||e_k||^2
#define WS_LOSS  132096      // 1 float loss accumulator
#define WS_CNT   132097      // 1 int rescue counter
#define WS_IDX   132100      // 131072 ints (16B aligned)
#define WS_LIST  263172      // 131072 ints rescue list
#define WS_EMBF  394244      // 131072 floats: bf16 hi/lo fragments

#define EPS_GAP  0.0078125f  // 2^-7: flag near-ties for exact fp32 rescore

typedef __attribute__((ext_vector_type(8))) short  short8;   // 8 x bf16
typedef __attribute__((ext_vector_type(4))) float  f32x4;

// round-to-nearest-even fp32 -> bf16 (no NaN handling; inputs are finite)
__device__ inline unsigned short f2bf(float f) {
    unsigned u = __float_as_uint(f);
    return (unsigned short)((u + 0x7FFFu + ((u >> 16) & 1u)) >> 16);
}
__device__ inline float bf2f(unsigned short h) {
    return __uint_as_float(((unsigned)h) << 16);
}

// ---------------------------------------------------------------------------
// prep: transpose embedding -> embT[C][K], compute 0.5*||e||^2,
// zero loss + rescue counter.
// ---------------------------------------------------------------------------
__global__ __launch_bounds__(128) void prep_kernel(const float* __restrict__ emb,
                                                   float* __restrict__ embT,
                                                   float* __restrict__ enh,
                                                   float* __restrict__ loss_acc,
                                                   int* __restrict__ cnt) {
    const int k = blockIdx.x;     // 0..1023
    const int c = threadIdx.x;    // 0..127
    float v = emb[k * CC + c];
    embT[c * KK + k] = v;
    float s = v * v;
    #pragma unroll
    for (int o = 32; o > 0; o >>= 1) s += __shfl_down(s, o);
    __shared__ float part[2];
    if ((c & 63) == 0) part[c >> 6] = s;
    __syncthreads();
    if (c == 0) {
        enh[k] = 0.5f * (part[0] + part[1]);
        if (k == 0) { *loss_acc = 0.0f; *cnt = 0; }
    }
}

// ---------------------------------------------------------------------------
// prep_emb: build codebook fragments (bf16 hi/lo) for mfma_f32_16x16x32_bf16.
// Used as the A operand: A[m = code-in-group][k = channel-in-chunk];
// per-lane: m = lane&15, k = (lane>>4)*8 + j, j=0..7.
// Layout: embF4[cc*512 + (kc*2+prec)*64 + lane], cc = code/16.
// ---------------------------------------------------------------------------
__global__ __launch_bounds__(256) void prep_emb_kernel(const float* __restrict__ emb,
                                                       short8* __restrict__ embF) {
    const int cc   = blockIdx.x;        // 0..63
    const int kc   = threadIdx.x >> 6;  // 0..3
    const int lane = threadIdx.x & 63;
    const int code = cc * 16 + (lane & 15);
    const int cb   = kc * 32 + (lane >> 4) * 8;
    const float* src = emb + code * CC + cb;
    short8 h, l;
    #pragma unroll
    for (int j = 0; j < 8; ++j) {
        float v = src[j];
        unsigned short hb = f2bf(v);
        float lo = v - bf2f(hb);
        h[j] = (short)hb;
        l[j] = (short)f2bf(lo);
    }
    embF[cc * 512 + (kc * 2 + 0) * 64 + lane] = h;
    embF[cc * 512 + (kc * 2 + 1) * 64 + lane] = l;
}

// ---------------------------------------------------------------------------
// argmin v8: swapped-operand split-bf16 MFMA, direct-from-L2 codebook,
// 64 VECTORS PER WAVE (4 M-tiles). Halves per-chip embF L2 traffic
// (2048 waves x 512 KB = 1.07 GB -> ~31 us L2 floor, below the 41 us MFMA
// floor) and gives 4 independent accumulator chains (ILP 4) to cover MFMA
// dependency latency. No LDS in the K-loop, no barriers -> race-free.
// A = codebook frags (L2), B = x frags (registers).
// D[row=code][col=vector]: col = lane&15 vector-in-tile, row = quad*4 + r
// the code. ~210 VGPR by audit; no waves_per_eu clamp (allocator headroom
// to 512 -> no spill; verify WRITE_SIZE stays ~0.56 MB).
// ---------------------------------------------------------------------------
__global__ __launch_bounds__(256)
void argmin_kernel(const float* __restrict__ x,
                   const float4* __restrict__ embF4,
                   const float* __restrict__ enh,
                   int* __restrict__ out_idx,
                   int* __restrict__ cnt,
                   int* __restrict__ list) {
    __shared__ float ehs[KK];         // 4 KB: 0.5*||e||^2 staged once

    const int t    = threadIdx.x;
    const int wave = t >> 6;
    const int lane = t & 63;
    const int quad = lane >> 4;
    const int l15  = lane & 15;

    const int n_wave = blockIdx.x * 256 + wave * 64;   // 64 vectors per wave
    const int b      = n_wave >> 15;
    const int dhw0   = n_wave & (DHW - 1);
    const float* __restrict__ xb = x + (size_t)b * CC * DHW + dhw0;

    #pragma unroll
    for (int j = 0; j < 4; ++j) ehs[j * 256 + t] = enh[j * 256 + t];

    // Build x fragments (B operand): B[k=quad*8+j][n=vec=l15] per tile.
    short8 x_hi[4][4], x_lo[4][4];
    #pragma unroll
    for (int tile = 0; tile < 4; ++tile) {
        const int voff = tile * 16 + l15;
        #pragma unroll
        for (int kc = 0; kc < 4; ++kc) {
            const int c0 = kc * 32 + quad * 8;
            #pragma unroll
            for (int j = 0; j < 8; ++j) {
                float v = xb[(size_t)(c0 + j) * DHW + voff];
                unsigned short hb = f2bf(v);
                float lo = v - bf2f(hb);
                x_hi[tile][kc][j] = (short)hb;
                x_lo[tile][kc][j] = (short)f2bf(lo);
            }
        }
    }

    // best-2 per lane, one vector per tile (v = tile*16 + l15), max-key form.
    float bv1[4] = {-1e30f, -1e30f, -1e30f, -1e30f};
    float bv2[4] = {-1e30f, -1e30f, -1e30f, -1e30f};
    int   bi1[4] = {0, 0, 0, 0};

    __syncthreads();  // ehs visible (the only block-wide sync in this kernel)

    #pragma unroll 2
    for (int cc = 0; cc < 64; ++cc) {
        // 8 codebook fragments for this 16-code group, straight from L2.
        const short8* src8 = (const short8*)(embF4 + cc * 512) + lane;
        const short8 bh0 = src8[0 * 64], bl0 = src8[1 * 64];
        const short8 bh1 = src8[2 * 64], bl1 = src8[3 * 64];
        const short8 bh2 = src8[4 * 64], bl2 = src8[5 * 64];
        const short8 bh3 = src8[6 * 64], bl3 = src8[7 * 64];

        // 0.5||e||^2 for this lane's 4 codes (rows quad*4..quad*4+3)
        const f32x4 ehv = *(const f32x4*)&ehs[cc * 16 + quad * 4];

        f32x4 acc0 = {0.f, 0.f, 0.f, 0.f};
        f32x4 acc1 = {0.f, 0.f, 0.f, 0.f};
        f32x4 acc2 = {0.f, 0.f, 0.f, 0.f};
        f32x4 acc3 = {0.f, 0.f, 0.f, 0.f};

        #define KC_STEP(BH, BL, KC)                                                      \
            acc0 = __builtin_amdgcn_mfma_f32_16x16x32_bf16(BH, x_hi[0][KC], acc0, 0, 0, 0); \
            acc1 = __builtin_amdgcn_mfma_f32_16x16x32_bf16(BH, x_hi[1][KC], acc1, 0, 0, 0); \
            acc2 = __builtin_amdgcn_mfma_f32_16x16x32_bf16(BH, x_hi[2][KC], acc2, 0, 0, 0); \
            acc3 = __builtin_amdgcn_mfma_f32_16x16x32_bf16(BH, x_hi[3][KC], acc3, 0, 0, 0); \
            acc0 = __builtin_amdgcn_mfma_f32_16x16x32_bf16(BH, x_lo[0][KC], acc0, 0, 0, 0); \
            acc1 = __builtin_amdgcn_mfma_f32_16x16x32_bf16(BH, x_lo[1][KC], acc1, 0, 0, 0); \
            acc2 = __builtin_amdgcn_mfma_f32_16x16x32_bf16(BH, x_lo[2][KC], acc2, 0, 0, 0); \
            acc3 = __builtin_amdgcn_mfma_f32_16x16x32_bf16(BH, x_lo[3][KC], acc3, 0, 0, 0); \
            acc0 = __builtin_amdgcn_mfma_f32_16x16x32_bf16(BL, x_hi[0][KC], acc0, 0, 0, 0); \
            acc1 = __builtin_amdgcn_mfma_f32_16x16x32_bf16(BL, x_hi[1][KC], acc1, 0, 0, 0); \
            acc2 = __builtin_amdgcn_mfma_f32_16x16x32_bf16(BL, x_hi[2][KC], acc2, 0, 0, 0); \
            acc3 = __builtin_amdgcn_mfma_f32_16x16x32_bf16(BL, x_hi[3][KC], acc3, 0, 0, 0);

        KC_STEP(bh0, bl0, 0)
        KC_STEP(bh1, bl1, 1)
        KC_STEP(bh2, bl2, 2)
        KC_STEP(bh3, bl3, 3)
        #undef KC_STEP

        // row = quad*4 + r = code-in-group; col = l15 = vector-in-tile
        const int cbase = cc * 16 + quad * 4;
        #pragma unroll
        for (int r = 0; r < 4; ++r) {
            const int code = cbase + r;
            const float eh = ehv[r];
            {
                const float k0 = acc0[r] - eh;
                bv2[0] = fminf(fmaxf(k0, bv2[0]), bv1[0]);
                if (k0 > bv1[0]) { bv1[0] = k0; bi1[0] = code; }
            }
            {
                const float k1 = acc1[r] - eh;
                bv2[1] = fminf(fmaxf(k1, bv2[1]), bv1[1]);
                if (k1 > bv1[1]) { bv1[1] = k1; bi1[1] = code; }
            }
            {
                const float k2 = acc2[r] - eh;
                bv2[2] = fminf(fmaxf(k2, bv2[2]), bv1[2]);
                if (k2 > bv1[2]) { bv1[2] = k2; bi1[2] = code; }
            }
            {
                const float k3 = acc3[r] - eh;
                bv2[3] = fminf(fmaxf(k3, bv2[3]), bv1[3]);
                if (k3 > bv1[3]) { bv1[3] = k3; bi1[3] = code; }
            }
        }
    }

    // Merge the 4 quads holding the same vector (lanes l15 + 16q).
    // Larger key wins; ties -> smaller index (argmax-first semantics).
    #pragma unroll
    for (int tile = 0; tile < 4; ++tile) {
        float v1 = bv1[tile], v2 = bv2[tile];
        int   i1 = bi1[tile];
        #pragma unroll
        for (int off = 16; off < 64; off <<= 1) {
            float ov1 = __shfl_xor(v1, off, 64);
            int   oi1 = __shfl_xor(i1, off, 64);
            float ov2 = __shfl_xor(v2, off, 64);
            bool take = (ov1 > v1) || (ov1 == v1 && oi1 < i1);
            float loser = take ? v1 : ov1;
            if (take) { v1 = ov1; i1 = oi1; }
            v2 = fmaxf(fmaxf(v2, ov2), loser);
        }
        if (lane < 16) {   // quad == 0 owns the write
            const int n = n_wave + tile * 16 + l15;
            out_idx[n] = i1;
            if (v1 - v2 < EPS_GAP) {   // key gap = m1 - m2
                int pos = atomicAdd(cnt, 1);
                list[pos] = n;
            }
        }
    }
}

// ---------------------------------------------------------------------------
// rescue: exact fp32 argmin for flagged near-tie vectors.
// Grid 512 (was 128): entries are processed block-serial, so parallelism
// scales rescue time by 1/4 when the flagged count is large.
// ---------------------------------------------------------------------------
__global__ __launch_bounds__(256) void rescue_kernel(const float* __restrict__ x,
                                                     const float* __restrict__ emb,
                                                     const float* __restrict__ enh,
                                                     const int* __restrict__ cnt,
                                                     const int* __restrict__ list,
                                                     int* __restrict__ out_idx) {
    __shared__ float xs[CC];
    __shared__ float rv[256];
    __shared__ int   ri[256];
    const int m = *cnt;
    for (int it = blockIdx.x; it < m; it += gridDim.x) {
        const int n   = list[it];
        const int b   = n >> 15;
        const int dhw = n & (DHW - 1);
        if (threadIdx.x < CC)
            xs[threadIdx.x] = x[(size_t)b * CC * DHW + (size_t)threadIdx.x * DHW + dhw];
        __syncthreads();
        float bv = 1e30f; int bi = 0;
        for (int k0 = 0; k0 < 4; ++k0) {
            const int k = k0 * 256 + threadIdx.x;
            const float* ek = emb + k * CC;
            float a0 = 0.f, a1 = 0.f, a2 = 0.f, a3 = 0.f;
            #pragma unroll
            for (int c = 0; c < CC; c += 4) {
                a0 = fmaf(xs[c + 0], ek[c + 0], a0);
                a1 = fmaf(xs[c + 1], ek[c + 1], a1);
                a2 = fmaf(xs[c + 2], ek[c + 2], a2);
                a3 = fmaf(xs[c + 3], ek[c + 3], a3);
            }
            const float key = enh[k] - ((a0 + a1) + (a2 + a3));
            if (key < bv || (key == bv && k < bi)) { bv = key; bi = k; }
        }
        rv[threadIdx.x] = bv; ri[threadIdx.x] = bi;
        __syncthreads();
        for (int s = 128; s > 0; s >>= 1) {
            if (threadIdx.x < s) {
                float ov = rv[threadIdx.x + s]; int oi = ri[threadIdx.x + s];
                if (ov < rv[threadIdx.x] ||
                    (ov == rv[threadIdx.x] && oi < ri[threadIdx.x])) {
                    rv[threadIdx.x] = ov; ri[threadIdx.x] = oi;
                }
            }
            __syncthreads();
        }
        if (threadIdx.x == 0) out_idx[n] = ri[0];
        __syncthreads();
    }
}

// ---------------------------------------------------------------------------
// quant: gather codes, write straight-through output, accumulate loss sum.
// ---------------------------------------------------------------------------
__global__ __launch_bounds__(256) void quant_kernel(const float* __restrict__ x,
                                                    const float* __restrict__ embT,
                                                    const int* __restrict__ idx,
                                                    float* __restrict__ out,
                                                    float* __restrict__ loss_acc) {
    const int bid   = blockIdx.x;           // 0..511
    const int c0    = (bid & 3) * 32;
    const int chunk = bid >> 2;             // 0..127
    const int b     = chunk >> 5;           // 0..3
    const int dhw   = (chunk & 31) * 1024 + threadIdx.x * 4;
    const int n     = b * DHW + dhw;
    const int4 kk   = *(const int4*)(idx + n);
    const size_t base = (size_t)b * CC * DHW + dhw;

    float lacc = 0.0f;
    for (int c = c0; c < c0 + 32; ++c) {
        const float4 in4 = *(const float4*)(x + base + (size_t)c * DHW);
        const float* er  = embT + c * KK;
        const float d0 = er[kk.x] - in4.x;
        const float d1 = er[kk.y] - in4.y;
        const float d2 = er[kk.z] - in4.z;
        const float d3 = er[kk.w] - in4.w;
        float4 o4;
        o4.x = in4.x + d0; o4.y = in4.y + d1;
        o4.z = in4.z + d2; o4.w = in4.w + d3;
        *(float4*)(out + base + (size_t)c * DHW) = o4;
        lacc += d0 * d0 + d1 * d1 + d2 * d2 + d3 * d3;
    }
    #pragma unroll
    for (int o = 32; o > 0; o >>= 1) lacc += __shfl_down(lacc, o);
    __shared__ float part[4];
    if ((threadIdx.x & 63) == 0) part[threadIdx.x >> 6] = lacc;
    __syncthreads();
    if (threadIdx.x == 0)
        atomicAdd(loss_acc, part[0] + part[1] + part[2] + part[3]);
}

// ---------------------------------------------------------------------------
// tail: indices as float, embedding copy, encodings_sum zeros, loss finalize
// ---------------------------------------------------------------------------
__global__ __launch_bounds__(256) void tail_kernel(const int* __restrict__ idx,
                                                   const float* __restrict__ emb,
                                                   const float* __restrict__ loss_acc,
                                                   float* __restrict__ out) {
    const int g = blockIdx.x * 256 + threadIdx.x;
    if (g < NN) {
        out[OUT_IDX + g] = (float)idx[g];
    } else if (g < 2 * NN) {
        out[OUT_EMB + (g - NN)] = emb[g - NN];
    } else if (g < 2 * NN + 256) {
        out[OUT_ESUM + (g - 2 * NN)] = 0.0f;
    } else if (g == 2 * NN + 256) {
        out[OUT_LOSS] = 2.5f * (*loss_acc) / 16777216.0f;
    }
}

extern "C" void kernel_launch(void* const* d_in, const int* in_sizes, int n_in,
                              void* d_out, int out_size, void* d_ws, size_t ws_size,
                              hipStream_t stream) {
    const float* x   = (const float*)d_in[0];   // [4,128,32,32,32] fp32
    const float* emb = (const float*)d_in[1];   // [1024,128] fp32
    float* out = (float*)d_out;
    float* ws  = (float*)d_ws;

    float*  embT     = ws + WS_EMBT;
    float*  enh      = ws + WS_ENH;
    float*  loss_acc = ws + WS_LOSS;
    int*    cnt      = (int*)(ws + WS_CNT);
    int*    idx      = (int*)(ws + WS_IDX);
    int*    list     = (int*)(ws + WS_LIST);
    float*  embF     = ws + WS_EMBF;

    prep_kernel<<<KK, 128, 0, stream>>>(emb, embT, enh, loss_acc, cnt);
    prep_emb_kernel<<<64, 256, 0, stream>>>(emb, (short8*)embF);
    argmin_kernel<<<NN / 256, 256, 0, stream>>>(x, (const float4*)embF, enh, idx, cnt, list);
    rescue_kernel<<<512, 256, 0, stream>>>(x, emb, enh, cnt, list, idx);
    quant_kernel<<<512, 256, 0, stream>>>(x, embT, idx, out, loss_acc);
    tail_kernel<<<(2 * NN + 256 + 256) / 256 + 1, 256, 0, stream>>>(idx, emb, loss_acc, out);
}

// Round 6
// 303.633 us; speedup vs baseline: 1.2310x; 1.2310x over previous
//
#include <hip/hip_runtime.h>

// Problem constants
#define BB   4
#define CC   128
#define DHW  32768           // 32*32*32
#define NN   131072          // BB*DHW
#define KK   1024

// Output layout (floats, concatenated in reference return order)
#define OUT_Q    0
#define OUT_LOSS 16777216
#define OUT_IDX  16777217
#define OUT_ESUM 16908289
#define OUT_EMB  16908545

// Workspace layout (float offsets). Total ~2.1 MB.
#define WS_ENH   131072      // 1024 floats: 0.5*||e_k||^2
#define WS_LOSS  132096      // 1 float loss accumulator
#define WS_CNT   132097      // 1 int rescue counter
#define WS_IDX   132100      // 131072 ints (16B aligned)
#define WS_LIST  263172      // 131072 ints rescue list
#define WS_EMBF  394244      // 131072 floats: bf16 hi/lo fragments

#define EPS_GAP  0.0078125f  // 2^-7: flag near-ties for exact fp32 rescore

typedef __attribute__((ext_vector_type(8))) short  short8;   // 8 x bf16
typedef __attribute__((ext_vector_type(4))) float  f32x4;

// round-to-nearest-even fp32 -> bf16 (no NaN handling; inputs are finite)
__device__ inline unsigned short f2bf(float f) {
    unsigned u = __float_as_uint(f);
    return (unsigned short)((u + 0x7FFFu + ((u >> 16) & 1u)) >> 16);
}
__device__ inline float bf2f(unsigned short h) {
    return __uint_as_float(((unsigned)h) << 16);
}

// ---------------------------------------------------------------------------
// prep: compute 0.5*||e||^2, zero loss + rescue counter. (embT removed: the
// quant kernel is fused into argmin's epilogue, which gathers emb row-major.)
// ---------------------------------------------------------------------------
__global__ __launch_bounds__(128) void prep_kernel(const float* __restrict__ emb,
                                                   float* __restrict__ enh,
                                                   float* __restrict__ loss_acc,
                                                   int* __restrict__ cnt) {
    const int k = blockIdx.x;     // 0..1023
    const int c = threadIdx.x;    // 0..127
    float v = emb[k * CC + c];
    float s = v * v;
    #pragma unroll
    for (int o = 32; o > 0; o >>= 1) s += __shfl_down(s, o);
    __shared__ float part[2];
    if ((c & 63) == 0) part[c >> 6] = s;
    __syncthreads();
    if (c == 0) {
        enh[k] = 0.5f * (part[0] + part[1]);
        if (k == 0) { *loss_acc = 0.0f; *cnt = 0; }
    }
}

// ---------------------------------------------------------------------------
// prep_emb: build codebook fragments (bf16 hi/lo) for mfma_f32_16x16x32_bf16.
// Used as the A operand: A[m = code-in-group][k = channel-in-chunk];
// per-lane: m = lane&15, k = (lane>>4)*8 + j, j=0..7.
// Layout: embF4[cc*512 + (kc*2+prec)*64 + lane], cc = code/16.
// ---------------------------------------------------------------------------
__global__ __launch_bounds__(256) void prep_emb_kernel(const float* __restrict__ emb,
                                                       short8* __restrict__ embF) {
    const int cc   = blockIdx.x;        // 0..63
    const int kc   = threadIdx.x >> 6;  // 0..3
    const int lane = threadIdx.x & 63;
    const int code = cc * 16 + (lane & 15);
    const int cb   = kc * 32 + (lane >> 4) * 8;
    const float* src = emb + code * CC + cb;
    short8 h, l;
    #pragma unroll
    for (int j = 0; j < 8; ++j) {
        float v = src[j];
        unsigned short hb = f2bf(v);
        float lo = v - bf2f(hb);
        h[j] = (short)hb;
        l[j] = (short)f2bf(lo);
    }
    embF[cc * 512 + (kc * 2 + 0) * 64 + lane] = h;
    embF[cc * 512 + (kc * 2 + 1) * 64 + lane] = l;
}

// ---------------------------------------------------------------------------
// argmin v9: R4's verified 32-vec/wave swapped-operand split-bf16 MFMA,
// direct-from-L2 codebook (race-free, no K-loop barriers), PLUS fused
// quantize epilogue:
//   - ||x||^2 per vector accumulated (fp32) during fragment build;
//   - loss contribution = ||x||^2 - 2*best_key  (since Sum(q-x)^2 =
//     ||x||^2 - 2*(x.e - 0.5||e||^2));
//   - straight-through output q = emb[idx] written directly (x + (q-x) == q
//     to 1 ulp);
// eliminating the separate quant kernel and its 67 MB x re-read.
// acc init = -0.5||e||^2 so key = acc[r] directly.
// ---------------------------------------------------------------------------
__global__ __launch_bounds__(256)
void argmin_kernel(const float* __restrict__ x,
                   const float4* __restrict__ embF4,
                   const float* __restrict__ enh,
                   const float* __restrict__ emb,
                   int* __restrict__ out_idx,
                   int* __restrict__ cnt,
                   int* __restrict__ list,
                   float* __restrict__ out,
                   float* __restrict__ loss_acc) {
    __shared__ float ehs[KK];         // 4 KB: 0.5*||e||^2 staged once
    __shared__ float lpart[4];

    const int t    = threadIdx.x;
    const int wave = t >> 6;
    const int lane = t & 63;
    const int quad = lane >> 4;
    const int l15  = lane & 15;

    const int n_wave = blockIdx.x * 128 + wave * 32;
    const int b      = n_wave >> 15;
    const int dhw0   = n_wave & (DHW - 1);
    const float* __restrict__ xb = x + (size_t)b * CC * DHW + dhw0;

    #pragma unroll
    for (int j = 0; j < 4; ++j) ehs[j * 256 + t] = enh[j * 256 + t];

    // Build x fragments (B operand): B[k=quad*8+j][n=vec=l15] per tile.
    // xsq[tile]: this lane's fp32 partial of ||x_vec||^2 (32 of 128 channels).
    short8 x_hi[2][4], x_lo[2][4];
    float xsq[2] = {0.f, 0.f};
    #pragma unroll
    for (int tile = 0; tile < 2; ++tile) {
        const int voff = tile * 16 + l15;
        #pragma unroll
        for (int kc = 0; kc < 4; ++kc) {
            const int c0 = kc * 32 + quad * 8;
            #pragma unroll
            for (int j = 0; j < 8; ++j) {
                float v = xb[(size_t)(c0 + j) * DHW + voff];
                xsq[tile] = fmaf(v, v, xsq[tile]);
                unsigned short hb = f2bf(v);
                float lo = v - bf2f(hb);
                x_hi[tile][kc][j] = (short)hb;
                x_lo[tile][kc][j] = (short)f2bf(lo);
            }
        }
    }

    // best-2 per lane, one vector per tile (v = tile*16 + l15), max-key form.
    float bv1[2] = {-1e30f, -1e30f};
    float bv2[2] = {-1e30f, -1e30f};
    int   bi1[2] = {0, 0};

    __syncthreads();  // ehs visible

    #pragma unroll 2
    for (int cc = 0; cc < 64; ++cc) {
        // 8 codebook fragments for this 16-code group, straight from L2.
        const short8* src8 = (const short8*)(embF4 + cc * 512) + lane;
        const short8 bh0 = src8[0 * 64], bl0 = src8[1 * 64];
        const short8 bh1 = src8[2 * 64], bl1 = src8[3 * 64];
        const short8 bh2 = src8[4 * 64], bl2 = src8[5 * 64];
        const short8 bh3 = src8[6 * 64], bl3 = src8[7 * 64];

        // key = x.e - 0.5||e||^2: fold the -0.5||e||^2 into the acc init.
        const f32x4 ehv = *(const f32x4*)&ehs[cc * 16 + quad * 4];
        f32x4 acc0 = -ehv;
        f32x4 acc1 = -ehv;

        #pragma unroll
        for (int kc = 0; kc < 4; ++kc) {
            const short8 bh = (kc == 0) ? bh0 : (kc == 1) ? bh1 : (kc == 2) ? bh2 : bh3;
            const short8 bl = (kc == 0) ? bl0 : (kc == 1) ? bl1 : (kc == 2) ? bl2 : bl3;
            acc0 = __builtin_amdgcn_mfma_f32_16x16x32_bf16(bh, x_hi[0][kc], acc0, 0, 0, 0);
            acc1 = __builtin_amdgcn_mfma_f32_16x16x32_bf16(bh, x_hi[1][kc], acc1, 0, 0, 0);
            acc0 = __builtin_amdgcn_mfma_f32_16x16x32_bf16(bh, x_lo[0][kc], acc0, 0, 0, 0);
            acc1 = __builtin_amdgcn_mfma_f32_16x16x32_bf16(bh, x_lo[1][kc], acc1, 0, 0, 0);
            acc0 = __builtin_amdgcn_mfma_f32_16x16x32_bf16(bl, x_hi[0][kc], acc0, 0, 0, 0);
            acc1 = __builtin_amdgcn_mfma_f32_16x16x32_bf16(bl, x_hi[1][kc], acc1, 0, 0, 0);
        }

        // row = quad*4 + r = code-in-group; col = l15 = vector-in-tile
        const int cbase = cc * 16 + quad * 4;
        #pragma unroll
        for (int r = 0; r < 4; ++r) {
            const int code = cbase + r;
            const float k0 = acc0[r];
            bv2[0] = fminf(fmaxf(k0, bv2[0]), bv1[0]);
            if (k0 > bv1[0]) { bv1[0] = k0; bi1[0] = code; }
            const float k1 = acc1[r];
            bv2[1] = fminf(fmaxf(k1, bv2[1]), bv1[1]);
            if (k1 > bv1[1]) { bv1[1] = k1; bi1[1] = code; }
        }
    }

    // Merge the 4 quads holding the same vector (lanes l15 + 16q); the xor
    // butterfly leaves ALL lanes with the merged result. Sum ||x||^2 along
    // the way (the 4 quads hold disjoint channel subsets).
    float lsum = 0.f;
    int mIdx[2];
    #pragma unroll
    for (int tile = 0; tile < 2; ++tile) {
        float v1 = bv1[tile], v2 = bv2[tile], xq = xsq[tile];
        int   i1 = bi1[tile];
        #pragma unroll
        for (int off = 16; off < 64; off <<= 1) {
            float ov1 = __shfl_xor(v1, off, 64);
            int   oi1 = __shfl_xor(i1, off, 64);
            float ov2 = __shfl_xor(v2, off, 64);
            xq += __shfl_xor(xq, off, 64);
            bool take = (ov1 > v1) || (ov1 == v1 && oi1 < i1);
            float loser = take ? v1 : ov1;
            if (take) { v1 = ov1; i1 = oi1; }
            v2 = fmaxf(fmaxf(v2, ov2), loser);
        }
        mIdx[tile] = i1;
        if (lane < 16) {   // quad 0 owns the vector
            const int n = n_wave + tile * 16 + l15;
            out_idx[n] = i1;
            lsum += xq - 2.0f * v1;            // Sum_c (q_c - x_c)^2
            if (v1 - v2 < EPS_GAP) {           // key gap = m1 - m2
                int pos = atomicAdd(cnt, 1);
                list[pos] = n;
            }
        }
    }

    // Block-level loss reduction -> one atomic per block.
    #pragma unroll
    for (int o = 32; o > 0; o >>= 1) lsum += __shfl_down(lsum, o);
    if (lane == 0) lpart[wave] = lsum;
    __syncthreads();
    if (t == 0)
        atomicAdd(loss_acc, lpart[0] + lpart[1] + lpart[2] + lpart[3]);

    // Fused quantize write: q = emb[idx][c], written channel-major so each
    // half-wave's 32 lanes hit consecutive dhw (128B segments).
    const int vv = lane & 31;           // vector-in-wave
    const int h  = lane >> 5;           // channel half (0: c<64, 1: c>=64)
    const int i0 = __shfl(mIdx[0], vv & 15, 64);
    const int i1 = __shfl(mIdx[1], vv & 15, 64);
    const int code = (vv < 16) ? i0 : i1;
    const float* er = emb + code * CC + h * 64;
    float* op = out + OUT_Q + (size_t)b * CC * DHW + (size_t)(h * 64) * DHW + dhw0 + vv;
    #pragma unroll 4
    for (int c4 = 0; c4 < 16; ++c4) {
        const float4 e4 = *(const float4*)(er + c4 * 4);
        op[(size_t)(c4 * 4 + 0) * DHW] = e4.x;
        op[(size_t)(c4 * 4 + 1) * DHW] = e4.y;
        op[(size_t)(c4 * 4 + 2) * DHW] = e4.z;
        op[(size_t)(c4 * 4 + 3) * DHW] = e4.w;
    }
}

// ---------------------------------------------------------------------------
// rescue: exact fp32 argmin for flagged near-tie vectors; rewrites both the
// index and the fused quantized-output row for its vectors. (Loss keeps the
// argmin-pass key: the rescued key differs by < EPS_GAP = 2^-7 -> negligible.)
// ---------------------------------------------------------------------------
__global__ __launch_bounds__(256) void rescue_kernel(const float* __restrict__ x,
                                                     const float* __restrict__ emb,
                                                     const float* __restrict__ enh,
                                                     const int* __restrict__ cnt,
                                                     const int* __restrict__ list,
                                                     int* __restrict__ out_idx,
                                                     float* __restrict__ out) {
    __shared__ float xs[CC];
    __shared__ float rv[256];
    __shared__ int   ri[256];
    const int m = *cnt;
    for (int it = blockIdx.x; it < m; it += gridDim.x) {
        const int n   = list[it];
        const int b   = n >> 15;
        const int dhw = n & (DHW - 1);
        if (threadIdx.x < CC)
            xs[threadIdx.x] = x[(size_t)b * CC * DHW + (size_t)threadIdx.x * DHW + dhw];
        __syncthreads();
        float bv = 1e30f; int bi = 0;
        for (int k0 = 0; k0 < 4; ++k0) {
            const int k = k0 * 256 + threadIdx.x;
            const float* ek = emb + k * CC;
            float a0 = 0.f, a1 = 0.f, a2 = 0.f, a3 = 0.f;
            #pragma unroll
            for (int c = 0; c < CC; c += 4) {
                a0 = fmaf(xs[c + 0], ek[c + 0], a0);
                a1 = fmaf(xs[c + 1], ek[c + 1], a1);
                a2 = fmaf(xs[c + 2], ek[c + 2], a2);
                a3 = fmaf(xs[c + 3], ek[c + 3], a3);
            }
            const float key = enh[k] - ((a0 + a1) + (a2 + a3));
            if (key < bv || (key == bv && k < bi)) { bv = key; bi = k; }
        }
        rv[threadIdx.x] = bv; ri[threadIdx.x] = bi;
        __syncthreads();
        for (int s = 128; s > 0; s >>= 1) {
            if (threadIdx.x < s) {
                float ov = rv[threadIdx.x + s]; int oi = ri[threadIdx.x + s];
                if (ov < rv[threadIdx.x] ||
                    (ov == rv[threadIdx.x] && oi < ri[threadIdx.x])) {
                    rv[threadIdx.x] = ov; ri[threadIdx.x] = oi;
                }
            }
            __syncthreads();
        }
        const int code = ri[0];
        if (threadIdx.x == 0) out_idx[n] = code;
        // rewrite the quantized row with the corrected code
        if (threadIdx.x < CC)
            out[OUT_Q + (size_t)b * CC * DHW + (size_t)threadIdx.x * DHW + dhw] =
                emb[code * CC + threadIdx.x];
        __syncthreads();
    }
}

// ---------------------------------------------------------------------------
// tail: indices as float, embedding copy, encodings_sum zeros, loss finalize
// ---------------------------------------------------------------------------
__global__ __launch_bounds__(256) void tail_kernel(const int* __restrict__ idx,
                                                   const float* __restrict__ emb,
                                                   const float* __restrict__ loss_acc,
                                                   float* __restrict__ out) {
    const int g = blockIdx.x * 256 + threadIdx.x;
    if (g < NN) {
        out[OUT_IDX + g] = (float)idx[g];
    } else if (g < 2 * NN) {
        out[OUT_EMB + (g - NN)] = emb[g - NN];
    } else if (g < 2 * NN + 256) {
        out[OUT_ESUM + (g - 2 * NN)] = 0.0f;
    } else if (g == 2 * NN + 256) {
        out[OUT_LOSS] = 2.5f * (*loss_acc) / 16777216.0f;
    }
}

extern "C" void kernel_launch(void* const* d_in, const int* in_sizes, int n_in,
                              void* d_out, int out_size, void* d_ws, size_t ws_size,
                              hipStream_t stream) {
    const float* x   = (const float*)d_in[0];   // [4,128,32,32,32] fp32
    const float* emb = (const float*)d_in[1];   // [1024,128] fp32
    float* out = (float*)d_out;
    float* ws  = (float*)d_ws;

    float*  enh      = ws + WS_ENH;
    float*  loss_acc = ws + WS_LOSS;
    int*    cnt      = (int*)(ws + WS_CNT);
    int*    idx      = (int*)(ws + WS_IDX);
    int*    list     = (int*)(ws + WS_LIST);
    float*  embF     = ws + WS_EMBF;

    prep_kernel<<<KK, 128, 0, stream>>>(emb, enh, loss_acc, cnt);
    prep_emb_kernel<<<64, 256, 0, stream>>>(emb, (short8*)embF);
    argmin_kernel<<<NN / 128, 256, 0, stream>>>(x, (const float4*)embF, enh, emb,
                                                idx, cnt, list, out, loss_acc);
    rescue_kernel<<<512, 256, 0, stream>>>(x, emb, enh, cnt, list, idx, out);
    tail_kernel<<<(2 * NN + 256 + 256) / 256 + 1, 256, 0, stream>>>(idx, emb, loss_acc, out);
}

// Round 7
// 261.049 us; speedup vs baseline: 1.4318x; 1.1631x over previous
//
#include <hip/hip_runtime.h>

// Problem constants
#define BB   4
#define CC   128
#define DHW  32768           // 32*32*32
#define NN   131072          // BB*DHW
#define KK   1024

// Output layout (floats, concatenated in reference return order)
#define OUT_Q    0
#define OUT_LOSS 16777216
#define OUT_IDX  16777217
#define OUT_ESUM 16908289
#define OUT_EMB  16908545

// Workspace layout (float offsets). Total ~2.1 MB.
#define WS_ENH   131072      // 1024 floats: 0.5*||e_k||^2
#define WS_LOSS  132096      // 1 float loss accumulator
#define WS_CNT   132097      // 1 int rescue counter
#define WS_IDX   132100      // 131072 ints (16B aligned)
#define WS_LIST  263172      // 131072 ints rescue list
#define WS_EMBF  394244      // 131072 floats: bf16 hi/lo fragments

// 2^-9: split-bf16 key error is <= ~3e-4 worst case (dropped lo*lo term +
// fp32 accum); 2^-9 = 1.95e-3 keeps ~6x margin while cutting the flagged
// near-tie count ~4x vs the old 2^-7.
#define EPS_GAP  0.001953125f

typedef __attribute__((ext_vector_type(8))) short  short8;   // 8 x bf16
typedef __attribute__((ext_vector_type(4))) float  f32x4;

// round-to-nearest-even fp32 -> bf16 (no NaN handling; inputs are finite)
__device__ inline unsigned short f2bf(float f) {
    unsigned u = __float_as_uint(f);
    return (unsigned short)((u + 0x7FFFu + ((u >> 16) & 1u)) >> 16);
}
__device__ inline float bf2f(unsigned short h) {
    return __uint_as_float(((unsigned)h) << 16);
}

// ---------------------------------------------------------------------------
// prep: compute 0.5*||e||^2, zero loss + rescue counter.
// ---------------------------------------------------------------------------
__global__ __launch_bounds__(128) void prep_kernel(const float* __restrict__ emb,
                                                   float* __restrict__ enh,
                                                   float* __restrict__ loss_acc,
                                                   int* __restrict__ cnt) {
    const int k = blockIdx.x;     // 0..1023
    const int c = threadIdx.x;    // 0..127
    float v = emb[k * CC + c];
    float s = v * v;
    #pragma unroll
    for (int o = 32; o > 0; o >>= 1) s += __shfl_down(s, o);
    __shared__ float part[2];
    if ((c & 63) == 0) part[c >> 6] = s;
    __syncthreads();
    if (c == 0) {
        enh[k] = 0.5f * (part[0] + part[1]);
        if (k == 0) { *loss_acc = 0.0f; *cnt = 0; }
    }
}

// ---------------------------------------------------------------------------
// prep_emb: build codebook fragments (bf16 hi/lo) for mfma_f32_16x16x32_bf16.
// Used as the A operand: A[m = code-in-group][k = channel-in-chunk];
// per-lane: m = lane&15, k = (lane>>4)*8 + j, j=0..7.
// Layout: embF4[cc*512 + (kc*2+prec)*64 + lane], cc = code/16.
// ---------------------------------------------------------------------------
__global__ __launch_bounds__(256) void prep_emb_kernel(const float* __restrict__ emb,
                                                       short8* __restrict__ embF) {
    const int cc   = blockIdx.x;        // 0..63
    const int kc   = threadIdx.x >> 6;  // 0..3
    const int lane = threadIdx.x & 63;
    const int code = cc * 16 + (lane & 15);
    const int cb   = kc * 32 + (lane >> 4) * 8;
    const float* src = emb + code * CC + cb;
    short8 h, l;
    #pragma unroll
    for (int j = 0; j < 8; ++j) {
        float v = src[j];
        unsigned short hb = f2bf(v);
        float lo = v - bf2f(hb);
        h[j] = (short)hb;
        l[j] = (short)f2bf(lo);
    }
    embF[cc * 512 + (kc * 2 + 0) * 64 + lane] = h;
    embF[cc * 512 + (kc * 2 + 1) * 64 + lane] = l;
}

// ---------------------------------------------------------------------------
// argmin v10: R4's verified 32-vec/wave swapped-operand split-bf16 MFMA,
// direct-from-L2 codebook, fused quantize epilogue. v10 change: the epilogue
// writes q via a 4x4 in-register transpose -- each lane owns 4 consecutive
// dhw x 16 channels, loads 4 emb float4s (L2-hot) and stores float4 along
// dhw. 16 float4 stores/lane vs v9's 128 scalar stores (8x fewer store
// instructions, full 128B-line coalescing across lanes).
// ---------------------------------------------------------------------------
__global__ __launch_bounds__(256)
void argmin_kernel(const float* __restrict__ x,
                   const float4* __restrict__ embF4,
                   const float* __restrict__ enh,
                   const float* __restrict__ emb,
                   int* __restrict__ out_idx,
                   int* __restrict__ cnt,
                   int* __restrict__ list,
                   float* __restrict__ out,
                   float* __restrict__ loss_acc) {
    __shared__ float ehs[KK];         // 4 KB: 0.5*||e||^2 staged once
    __shared__ float lpart[4];

    const int t    = threadIdx.x;
    const int wave = t >> 6;
    const int lane = t & 63;
    const int quad = lane >> 4;
    const int l15  = lane & 15;

    const int n_wave = blockIdx.x * 128 + wave * 32;
    const int b      = n_wave >> 15;
    const int dhw0   = n_wave & (DHW - 1);
    const float* __restrict__ xb = x + (size_t)b * CC * DHW + dhw0;

    #pragma unroll
    for (int j = 0; j < 4; ++j) ehs[j * 256 + t] = enh[j * 256 + t];

    // Build x fragments (B operand): B[k=quad*8+j][n=vec=l15] per tile.
    // xsq[tile]: this lane's fp32 partial of ||x_vec||^2 (32 of 128 channels).
    short8 x_hi[2][4], x_lo[2][4];
    float xsq[2] = {0.f, 0.f};
    #pragma unroll
    for (int tile = 0; tile < 2; ++tile) {
        const int voff = tile * 16 + l15;
        #pragma unroll
        for (int kc = 0; kc < 4; ++kc) {
            const int c0 = kc * 32 + quad * 8;
            #pragma unroll
            for (int j = 0; j < 8; ++j) {
                float v = xb[(size_t)(c0 + j) * DHW + voff];
                xsq[tile] = fmaf(v, v, xsq[tile]);
                unsigned short hb = f2bf(v);
                float lo = v - bf2f(hb);
                x_hi[tile][kc][j] = (short)hb;
                x_lo[tile][kc][j] = (short)f2bf(lo);
            }
        }
    }

    // best-2 per lane, one vector per tile (v = tile*16 + l15), max-key form.
    float bv1[2] = {-1e30f, -1e30f};
    float bv2[2] = {-1e30f, -1e30f};
    int   bi1[2] = {0, 0};

    __syncthreads();  // ehs visible

    #pragma unroll 2
    for (int cc = 0; cc < 64; ++cc) {
        // 8 codebook fragments for this 16-code group, straight from L2.
        const short8* src8 = (const short8*)(embF4 + cc * 512) + lane;
        const short8 bh0 = src8[0 * 64], bl0 = src8[1 * 64];
        const short8 bh1 = src8[2 * 64], bl1 = src8[3 * 64];
        const short8 bh2 = src8[4 * 64], bl2 = src8[5 * 64];
        const short8 bh3 = src8[6 * 64], bl3 = src8[7 * 64];

        // key = x.e - 0.5||e||^2: fold the -0.5||e||^2 into the acc init.
        const f32x4 ehv = *(const f32x4*)&ehs[cc * 16 + quad * 4];
        f32x4 acc0 = -ehv;
        f32x4 acc1 = -ehv;

        #pragma unroll
        for (int kc = 0; kc < 4; ++kc) {
            const short8 bh = (kc == 0) ? bh0 : (kc == 1) ? bh1 : (kc == 2) ? bh2 : bh3;
            const short8 bl = (kc == 0) ? bl0 : (kc == 1) ? bl1 : (kc == 2) ? bl2 : bl3;
            acc0 = __builtin_amdgcn_mfma_f32_16x16x32_bf16(bh, x_hi[0][kc], acc0, 0, 0, 0);
            acc1 = __builtin_amdgcn_mfma_f32_16x16x32_bf16(bh, x_hi[1][kc], acc1, 0, 0, 0);
            acc0 = __builtin_amdgcn_mfma_f32_16x16x32_bf16(bh, x_lo[0][kc], acc0, 0, 0, 0);
            acc1 = __builtin_amdgcn_mfma_f32_16x16x32_bf16(bh, x_lo[1][kc], acc1, 0, 0, 0);
            acc0 = __builtin_amdgcn_mfma_f32_16x16x32_bf16(bl, x_hi[0][kc], acc0, 0, 0, 0);
            acc1 = __builtin_amdgcn_mfma_f32_16x16x32_bf16(bl, x_hi[1][kc], acc1, 0, 0, 0);
        }

        // row = quad*4 + r = code-in-group; col = l15 = vector-in-tile
        const int cbase = cc * 16 + quad * 4;
        #pragma unroll
        for (int r = 0; r < 4; ++r) {
            const int code = cbase + r;
            const float k0 = acc0[r];
            bv2[0] = fminf(fmaxf(k0, bv2[0]), bv1[0]);
            if (k0 > bv1[0]) { bv1[0] = k0; bi1[0] = code; }
            const float k1 = acc1[r];
            bv2[1] = fminf(fmaxf(k1, bv2[1]), bv1[1]);
            if (k1 > bv1[1]) { bv1[1] = k1; bi1[1] = code; }
        }
    }

    // Merge the 4 quads holding the same vector (lanes l15 + 16q); the xor
    // butterfly leaves ALL lanes with the merged result. Sum ||x||^2 along
    // the way (the 4 quads hold disjoint channel subsets).
    float lsum = 0.f;
    int mIdx[2];
    #pragma unroll
    for (int tile = 0; tile < 2; ++tile) {
        float v1 = bv1[tile], v2 = bv2[tile], xq = xsq[tile];
        int   i1 = bi1[tile];
        #pragma unroll
        for (int off = 16; off < 64; off <<= 1) {
            float ov1 = __shfl_xor(v1, off, 64);
            int   oi1 = __shfl_xor(i1, off, 64);
            float ov2 = __shfl_xor(v2, off, 64);
            xq += __shfl_xor(xq, off, 64);
            bool take = (ov1 > v1) || (ov1 == v1 && oi1 < i1);
            float loser = take ? v1 : ov1;
            if (take) { v1 = ov1; i1 = oi1; }
            v2 = fmaxf(fmaxf(v2, ov2), loser);
        }
        mIdx[tile] = i1;
        if (lane < 16) {   // quad 0 owns the vector
            const int n = n_wave + tile * 16 + l15;
            out_idx[n] = i1;
            lsum += xq - 2.0f * v1;            // Sum_c (q_c - x_c)^2
            if (v1 - v2 < EPS_GAP) {           // key gap = m1 - m2
                int pos = atomicAdd(cnt, 1);
                list[pos] = n;
            }
        }
    }

    // Block-level loss reduction -> one atomic per block.
    #pragma unroll
    for (int o = 32; o > 0; o >>= 1) lsum += __shfl_down(lsum, o);
    if (lane == 0) lpart[wave] = lsum;
    __syncthreads();
    if (t == 0)
        atomicAdd(loss_acc, lpart[0] + lpart[1] + lpart[2] + lpart[3]);

    // Fused quantize write, 4x4 transpose form. Lane owns 4 consecutive
    // vectors (dhw quad vq = lane&7) x 16 channels (block cb = lane>>3).
    // Per c-quad: 4 emb float4 loads (L2-hot) -> transpose -> 4 float4
    // stores along dhw. Lanes 0..7 of a channel block cover 8x16B = 128B.
    {
        const int vq = lane & 7;          // vector quad: vectors 4vq..4vq+3
        const int cb = lane >> 3;         // channel block: channels cb*16..+15
        int code[4];
        #pragma unroll
        for (int j = 0; j < 4; ++j) {
            const int w  = (4 * vq + j) & 15;
            const int cA = __shfl(mIdx[0], w, 64);
            const int cB = __shfl(mIdx[1], w, 64);
            code[j] = (vq < 4) ? cA : cB;
        }
        const float* e0 = emb + code[0] * CC + cb * 16;
        const float* e1 = emb + code[1] * CC + cb * 16;
        const float* e2 = emb + code[2] * CC + cb * 16;
        const float* e3 = emb + code[3] * CC + cb * 16;
        float* op = out + OUT_Q + (size_t)b * CC * DHW + (size_t)(cb * 16) * DHW
                    + dhw0 + 4 * vq;
        #pragma unroll
        for (int cq = 0; cq < 4; ++cq) {
            const float4 r0 = *(const float4*)(e0 + cq * 4);
            const float4 r1 = *(const float4*)(e1 + cq * 4);
            const float4 r2 = *(const float4*)(e2 + cq * 4);
            const float4 r3 = *(const float4*)(e3 + cq * 4);
            *(float4*)(op + (size_t)(cq * 4 + 0) * DHW) = make_float4(r0.x, r1.x, r2.x, r3.x);
            *(float4*)(op + (size_t)(cq * 4 + 1) * DHW) = make_float4(r0.y, r1.y, r2.y, r3.y);
            *(float4*)(op + (size_t)(cq * 4 + 2) * DHW) = make_float4(r0.z, r1.z, r2.z, r3.z);
            *(float4*)(op + (size_t)(cq * 4 + 3) * DHW) = make_float4(r0.w, r1.w, r2.w, r3.w);
        }
    }
}

// ---------------------------------------------------------------------------
// rescue v2: exact fp32 argmin for flagged near-tie vectors, BATCHED 4
// entries per block so the per-block 512 KB emb sweep (the L2-BW cost) is
// amortized 4x. Rewrites both the index and the quantized-output row.
// All register arrays statically indexed (unrolled e).
// ---------------------------------------------------------------------------
#define RENT 4
__global__ __launch_bounds__(256) void rescue_kernel(const float* __restrict__ x,
                                                     const float* __restrict__ emb,
                                                     const float* __restrict__ enh,
                                                     const int* __restrict__ cnt,
                                                     const int* __restrict__ list,
                                                     int* __restrict__ out_idx,
                                                     float* __restrict__ out) {
    __shared__ float xs[RENT][CC];
    __shared__ int   ns[RENT];
    __shared__ float rv[256];
    __shared__ int   ri[256];
    const int m = *cnt;
    const int t = threadIdx.x;

    for (int base = blockIdx.x * RENT; base < m; base += gridDim.x * RENT) {
        const int nb = min(RENT, m - base);

        // load x-vectors: threads t>>7 (2 lanes of 128) cover entries 0,2 / 1,3
        for (int e = t >> 7; e < nb; e += 2) {
            const int n   = list[base + e];
            const int bb  = n >> 15;
            const int dhw = n & (DHW - 1);
            xs[e][t & 127] = x[(size_t)bb * CC * DHW + (size_t)(t & 127) * DHW + dhw];
            if ((t & 127) == 0) ns[e] = n;
        }
        __syncthreads();

        float bv[RENT] = {1e30f, 1e30f, 1e30f, 1e30f};
        int   bi[RENT] = {0, 0, 0, 0};
        for (int k0 = 0; k0 < 4; ++k0) {
            const int k = k0 * 256 + t;
            const float* ek = emb + k * CC;
            float a0 = 0.f, a1 = 0.f, a2 = 0.f, a3 = 0.f;
            #pragma unroll 8
            for (int c = 0; c < CC; ++c) {
                const float ev = ek[c];
                a0 = fmaf(xs[0][c], ev, a0);
                a1 = fmaf(xs[1][c], ev, a1);
                a2 = fmaf(xs[2][c], ev, a2);
                a3 = fmaf(xs[3][c], ev, a3);
            }
            const float eh = enh[k];
            const float key0 = eh - a0;
            if (key0 < bv[0] || (key0 == bv[0] && k < bi[0])) { bv[0] = key0; bi[0] = k; }
            const float key1 = eh - a1;
            if (key1 < bv[1] || (key1 == bv[1] && k < bi[1])) { bv[1] = key1; bi[1] = k; }
            const float key2 = eh - a2;
            if (key2 < bv[2] || (key2 == bv[2] && k < bi[2])) { bv[2] = key2; bi[2] = k; }
            const float key3 = eh - a3;
            if (key3 < bv[3] || (key3 == bv[3] && k < bi[3])) { bv[3] = key3; bi[3] = k; }
        }

        #pragma unroll
        for (int e = 0; e < RENT; ++e) {
            if (e >= nb) break;
            __syncthreads();                 // rv/ri safe to overwrite
            rv[t] = bv[e]; ri[t] = bi[e];
            __syncthreads();
            for (int s = 128; s > 0; s >>= 1) {
                if (t < s) {
                    float ov = rv[t + s]; int oi = ri[t + s];
                    if (ov < rv[t] || (ov == rv[t] && oi < ri[t])) {
                        rv[t] = ov; ri[t] = oi;
                    }
                }
                __syncthreads();
            }
            const int code = ri[0];
            const int n    = ns[e];
            const int bb   = n >> 15;
            const int dhw  = n & (DHW - 1);
            if (t == 0) out_idx[n] = code;
            if (t < CC)
                out[OUT_Q + (size_t)bb * CC * DHW + (size_t)t * DHW + dhw] =
                    emb[code * CC + t];
        }
        __syncthreads();  // xs/ns safe to overwrite next batch
    }
}

// ---------------------------------------------------------------------------
// tail: indices as float, embedding copy, encodings_sum zeros, loss finalize
// ---------------------------------------------------------------------------
__global__ __launch_bounds__(256) void tail_kernel(const int* __restrict__ idx,
                                                   const float* __restrict__ emb,
                                                   const float* __restrict__ loss_acc,
                                                   float* __restrict__ out) {
    const int g = blockIdx.x * 256 + threadIdx.x;
    if (g < NN) {
        out[OUT_IDX + g] = (float)idx[g];
    } else if (g < 2 * NN) {
        out[OUT_EMB + (g - NN)] = emb[g - NN];
    } else if (g < 2 * NN + 256) {
        out[OUT_ESUM + (g - 2 * NN)] = 0.0f;
    } else if (g == 2 * NN + 256) {
        out[OUT_LOSS] = 2.5f * (*loss_acc) / 16777216.0f;
    }
}

extern "C" void kernel_launch(void* const* d_in, const int* in_sizes, int n_in,
                              void* d_out, int out_size, void* d_ws, size_t ws_size,
                              hipStream_t stream) {
    const float* x   = (const float*)d_in[0];   // [4,128,32,32,32] fp32
    const float* emb = (const float*)d_in[1];   // [1024,128] fp32
    float* out = (float*)d_out;
    float* ws  = (float*)d_ws;

    float*  enh      = ws + WS_ENH;
    float*  loss_acc = ws + WS_LOSS;
    int*    cnt      = (int*)(ws + WS_CNT);
    int*    idx      = (int*)(ws + WS_IDX);
    int*    list     = (int*)(ws + WS_LIST);
    float*  embF     = ws + WS_EMBF;

    prep_kernel<<<KK, 128, 0, stream>>>(emb, enh, loss_acc, cnt);
    prep_emb_kernel<<<64, 256, 0, stream>>>(emb, (short8*)embF);
    argmin_kernel<<<NN / 128, 256, 0, stream>>>(x, (const float4*)embF, enh, emb,
                                                idx, cnt, list, out, loss_acc);
    rescue_kernel<<<512, 256, 0, stream>>>(x, emb, enh, cnt, list, idx, out);
    tail_kernel<<<(2 * NN + 256 + 256) / 256 + 1, 256, 0, stream>>>(idx, emb, loss_acc, out);
}

// Round 8
// 248.502 us; speedup vs baseline: 1.5041x; 1.0505x over previous
//
#include <hip/hip_runtime.h>

// Problem constants
#define BB   4
#define CC   128
#define DHW  32768           // 32*32*32
#define NN   131072          // BB*DHW
#define KK   1024

// Output layout (floats, concatenated in reference return order)
#define OUT_Q    0
#define OUT_LOSS 16777216
#define OUT_IDX  16777217
#define OUT_ESUM 16908289
#define OUT_EMB  16908545

// Workspace layout (float offsets).
#define WS_ENH   131072      // 1024 floats: 0.5*||e_k||^2
#define WS_LOSS  132096      // 1 float loss accumulator
#define WS_CNT   132097      // 1 int rescue counter
#define WS_LIST  263172      // 131072 ints rescue list
#define WS_EMBH  394244      // 65536 floats: fp16 codebook fragments (256 KB)

// fp16 single-product key error: sigma ~0.006 (2^-11 inputs, fp32 accum,
// 128 terms). EPS = 0.0625 ~ 10 sigma: flagged set is a guaranteed superset
// of ambiguous vectors; expected flag rate ~1-2% (gap density ~1/4 near 0),
// one batched rescue sweep absorbs it.
#define EPS_GAP  0.0625f

typedef __attribute__((ext_vector_type(8))) short     short8;
typedef __attribute__((ext_vector_type(8))) _Float16  half8;   // 8 x fp16
typedef __attribute__((ext_vector_type(4))) float     f32x4;

// ---------------------------------------------------------------------------
// prep: one sweep over emb builds EVERYTHING emb-derived:
//  - fp16 A-operand fragments for mfma_f32_16x16x32_f16
//    (A[m=code-in-group][k=channel]; per-lane m=lane&15, k=(lane>>4)*8+j;
//     layout embH[cc*256 + kc*64 + lane], cc = code/16, kc = K-chunk of 32)
//  - enh[k] = 0.5*||e_k||^2
//  - OUT_EMB copy, OUT_ESUM zeros, loss/cnt zero (block 0)
// ---------------------------------------------------------------------------
__global__ __launch_bounds__(256) void prep_kernel(const float* __restrict__ emb,
                                                   half8* __restrict__ embH,
                                                   float* __restrict__ enh,
                                                   float* __restrict__ loss_acc,
                                                   int* __restrict__ cnt,
                                                   float* __restrict__ out) {
    const int cc   = blockIdx.x;        // 0..63 (16 codes each)
    const int t    = threadIdx.x;
    const int kc   = t >> 6;            // 0..3
    const int lane = t & 63;
    const int l15  = lane & 15;
    const int code = cc * 16 + l15;
    const int cb   = kc * 32 + (lane >> 4) * 8;
    const float* src = emb + code * CC + cb;

    half8 h;
    float s = 0.f;
    #pragma unroll
    for (int j = 0; j < 8; ++j) {
        float v = src[j];
        s = fmaf(v, v, s);
        h[j] = (_Float16)v;
    }
    embH[cc * 256 + kc * 64 + lane] = h;

    // reduce ||e||^2 per code: within wave over the 4 quads, then across waves
    s += __shfl_xor(s, 16, 64);
    s += __shfl_xor(s, 32, 64);
    __shared__ float part[4][16];
    if (lane < 16) part[kc][l15] = s;
    __syncthreads();
    if (t < 16)
        enh[cc * 16 + t] = 0.5f * (part[0][t] + part[1][t] + part[2][t] + part[3][t]);

    // OUT_EMB copy: this block's 2048-float slice (2 float4 per thread)
    {
        const float4* es = (const float4*)(emb + cc * 2048) + t;
        float4*       eo = (float4*)(out + OUT_EMB + cc * 2048) + t;
        eo[0]   = es[0];
        eo[256] = es[256];
    }
    if (cc == 0) {
        if (t == 0) { *loss_acc = 0.0f; *cnt = 0; }
        // OUT_ESUM zeros (256 floats)
        out[OUT_ESUM + t] = 0.0f;
    }
}

// ---------------------------------------------------------------------------
// argmin v11: single-product fp16 MFMA (was split-bf16 3-product).
// A = fp16 codebook frags (direct from L2, 256 KB total), B = fp16 x frags
// (registers, 32 VGPRs). D[row=code][col=vector]. Per 16-code group:
// 4 loads (16 B) + 8 MFMAs (was 8 loads + 24 MFMAs). No K-loop barriers.
// Key error handled by EPS-gated exact fp32 rescue.
// Fused epilogue: float idx write, loss contribution ||x||^2 - 2*best_key,
// quantized output via 4x4 in-register transpose stores.
// ---------------------------------------------------------------------------
__global__ __launch_bounds__(256)
void argmin_kernel(const float* __restrict__ x,
                   const half8* __restrict__ embH,
                   const float* __restrict__ enh,
                   const float* __restrict__ emb,
                   int* __restrict__ cnt,
                   int* __restrict__ list,
                   float* __restrict__ out,
                   float* __restrict__ loss_acc) {
    __shared__ float ehs[KK];         // 4 KB: 0.5*||e||^2 staged once
    __shared__ float lpart[4];

    const int t    = threadIdx.x;
    const int wave = t >> 6;
    const int lane = t & 63;
    const int quad = lane >> 4;
    const int l15  = lane & 15;

    const int n_wave = blockIdx.x * 128 + wave * 32;
    const int b      = n_wave >> 15;
    const int dhw0   = n_wave & (DHW - 1);
    const float* __restrict__ xb = x + (size_t)b * CC * DHW + dhw0;

    #pragma unroll
    for (int j = 0; j < 4; ++j) ehs[j * 256 + t] = enh[j * 256 + t];

    // Build x fragments (B operand, fp16): B[k=quad*8+j][n=vec=l15] per tile.
    // xsq[tile]: fp32 partial of ||x_vec||^2 (this lane's 32 of 128 channels).
    half8 x_h[2][4];
    float xsq[2] = {0.f, 0.f};
    #pragma unroll
    for (int tile = 0; tile < 2; ++tile) {
        const int voff = tile * 16 + l15;
        #pragma unroll
        for (int kc = 0; kc < 4; ++kc) {
            const int c0 = kc * 32 + quad * 8;
            #pragma unroll
            for (int j = 0; j < 8; ++j) {
                float v = xb[(size_t)(c0 + j) * DHW + voff];
                xsq[tile] = fmaf(v, v, xsq[tile]);
                x_h[tile][kc][j] = (_Float16)v;
            }
        }
    }

    // best-2 per lane, one vector per tile (v = tile*16 + l15), max-key form.
    float bv1[2] = {-1e30f, -1e30f};
    float bv2[2] = {-1e30f, -1e30f};
    int   bi1[2] = {0, 0};

    __syncthreads();  // ehs visible

    #pragma unroll 2
    for (int cc = 0; cc < 64; ++cc) {
        // 4 fp16 codebook fragments for this 16-code group (L2-hot;
        // base + immediate offsets 0/1024/2048/3072 B).
        const half8* src8 = embH + cc * 256 + lane;
        const half8 b0 = src8[0 * 64];
        const half8 b1 = src8[1 * 64];
        const half8 b2 = src8[2 * 64];
        const half8 b3 = src8[3 * 64];

        // key = x.e - 0.5||e||^2: fold -0.5||e||^2 into the acc init.
        const f32x4 ehv = *(const f32x4*)&ehs[cc * 16 + quad * 4];
        f32x4 acc0 = -ehv;
        f32x4 acc1 = -ehv;

        acc0 = __builtin_amdgcn_mfma_f32_16x16x32_f16(b0, x_h[0][0], acc0, 0, 0, 0);
        acc1 = __builtin_amdgcn_mfma_f32_16x16x32_f16(b0, x_h[1][0], acc1, 0, 0, 0);
        acc0 = __builtin_amdgcn_mfma_f32_16x16x32_f16(b1, x_h[0][1], acc0, 0, 0, 0);
        acc1 = __builtin_amdgcn_mfma_f32_16x16x32_f16(b1, x_h[1][1], acc1, 0, 0, 0);
        acc0 = __builtin_amdgcn_mfma_f32_16x16x32_f16(b2, x_h[0][2], acc0, 0, 0, 0);
        acc1 = __builtin_amdgcn_mfma_f32_16x16x32_f16(b2, x_h[1][2], acc1, 0, 0, 0);
        acc0 = __builtin_amdgcn_mfma_f32_16x16x32_f16(b3, x_h[0][3], acc0, 0, 0, 0);
        acc1 = __builtin_amdgcn_mfma_f32_16x16x32_f16(b3, x_h[1][3], acc1, 0, 0, 0);

        // row = quad*4 + r = code-in-group; col = l15 = vector-in-tile
        const int cbase = cc * 16 + quad * 4;
        #pragma unroll
        for (int r = 0; r < 4; ++r) {
            const int code = cbase + r;
            const float k0 = acc0[r];
            bv2[0] = fminf(fmaxf(k0, bv2[0]), bv1[0]);
            if (k0 > bv1[0]) { bv1[0] = k0; bi1[0] = code; }
            const float k1 = acc1[r];
            bv2[1] = fminf(fmaxf(k1, bv2[1]), bv1[1]);
            if (k1 > bv1[1]) { bv1[1] = k1; bi1[1] = code; }
        }
    }

    // Merge the 4 quads holding the same vector (lanes l15 + 16q); butterfly
    // leaves all lanes with the merged result. Sum ||x||^2 along the way.
    float lsum = 0.f;
    int mIdx[2];
    #pragma unroll
    for (int tile = 0; tile < 2; ++tile) {
        float v1 = bv1[tile], v2 = bv2[tile], xq = xsq[tile];
        int   i1 = bi1[tile];
        #pragma unroll
        for (int off = 16; off < 64; off <<= 1) {
            float ov1 = __shfl_xor(v1, off, 64);
            int   oi1 = __shfl_xor(i1, off, 64);
            float ov2 = __shfl_xor(v2, off, 64);
            xq += __shfl_xor(xq, off, 64);
            bool take = (ov1 > v1) || (ov1 == v1 && oi1 < i1);
            float loser = take ? v1 : ov1;
            if (take) { v1 = ov1; i1 = oi1; }
            v2 = fmaxf(fmaxf(v2, ov2), loser);
        }
        mIdx[tile] = i1;
        if (lane < 16) {   // quad 0 owns the vector
            const int n = n_wave + tile * 16 + l15;
            out[OUT_IDX + n] = (float)i1;
            lsum += xq - 2.0f * v1;            // Sum_c (q_c - x_c)^2
            if (v1 - v2 < EPS_GAP) {           // near-tie -> exact rescore
                int pos = atomicAdd(cnt, 1);
                list[pos] = n;
            }
        }
    }

    // Block-level loss reduction -> one atomic per block.
    #pragma unroll
    for (int o = 32; o > 0; o >>= 1) lsum += __shfl_down(lsum, o);
    if (lane == 0) lpart[wave] = lsum;
    __syncthreads();
    if (t == 0)
        atomicAdd(loss_acc, lpart[0] + lpart[1] + lpart[2] + lpart[3]);

    // Fused quantize write, 4x4 transpose form. Lane owns 4 consecutive
    // vectors (vq = lane&7) x 16 channels (cb = lane>>3); per c-quad: 4 emb
    // float4 loads (L2-hot) -> transpose -> 4 float4 stores along dhw.
    {
        const int vq = lane & 7;
        const int cb = lane >> 3;
        int code[4];
        #pragma unroll
        for (int j = 0; j < 4; ++j) {
            const int w  = (4 * vq + j) & 15;
            const int cA = __shfl(mIdx[0], w, 64);
            const int cB = __shfl(mIdx[1], w, 64);
            code[j] = (vq < 4) ? cA : cB;
        }
        const float* e0 = emb + code[0] * CC + cb * 16;
        const float* e1 = emb + code[1] * CC + cb * 16;
        const float* e2 = emb + code[2] * CC + cb * 16;
        const float* e3 = emb + code[3] * CC + cb * 16;
        float* op = out + OUT_Q + (size_t)b * CC * DHW + (size_t)(cb * 16) * DHW
                    + dhw0 + 4 * vq;
        #pragma unroll
        for (int cq = 0; cq < 4; ++cq) {
            const float4 r0 = *(const float4*)(e0 + cq * 4);
            const float4 r1 = *(const float4*)(e1 + cq * 4);
            const float4 r2 = *(const float4*)(e2 + cq * 4);
            const float4 r3 = *(const float4*)(e3 + cq * 4);
            *(float4*)(op + (size_t)(cq * 4 + 0) * DHW) = make_float4(r0.x, r1.x, r2.x, r3.x);
            *(float4*)(op + (size_t)(cq * 4 + 1) * DHW) = make_float4(r0.y, r1.y, r2.y, r3.y);
            *(float4*)(op + (size_t)(cq * 4 + 2) * DHW) = make_float4(r0.z, r1.z, r2.z, r3.z);
            *(float4*)(op + (size_t)(cq * 4 + 3) * DHW) = make_float4(r0.w, r1.w, r2.w, r3.w);
        }
    }
}

// ---------------------------------------------------------------------------
// rescue: exact fp32 argmin for flagged near-tie vectors, batched 4/block.
// Rewrites the float index and the quantized-output row. Also finalizes the
// loss scalar (loss_acc is complete once argmin finished; block 0 writes it).
// ---------------------------------------------------------------------------
#define RENT 4
__global__ __launch_bounds__(256) void rescue_kernel(const float* __restrict__ x,
                                                     const float* __restrict__ emb,
                                                     const float* __restrict__ enh,
                                                     const int* __restrict__ cnt,
                                                     const int* __restrict__ list,
                                                     const float* __restrict__ loss_acc,
                                                     float* __restrict__ out) {
    __shared__ float xs[RENT][CC];
    __shared__ int   ns[RENT];
    __shared__ float rv[256];
    __shared__ int   ri[256];
    const int m = *cnt;
    const int t = threadIdx.x;

    if (blockIdx.x == 0 && t == 0)
        out[OUT_LOSS] = 2.5f * (*loss_acc) / 16777216.0f;

    for (int base = blockIdx.x * RENT; base < m; base += gridDim.x * RENT) {
        const int nb = min(RENT, m - base);

        for (int e = t >> 7; e < nb; e += 2) {
            const int n   = list[base + e];
            const int bb  = n >> 15;
            const int dhw = n & (DHW - 1);
            xs[e][t & 127] = x[(size_t)bb * CC * DHW + (size_t)(t & 127) * DHW + dhw];
            if ((t & 127) == 0) ns[e] = n;
        }
        __syncthreads();

        float bv[RENT] = {1e30f, 1e30f, 1e30f, 1e30f};
        int   bi[RENT] = {0, 0, 0, 0};
        for (int k0 = 0; k0 < 4; ++k0) {
            const int k = k0 * 256 + t;
            const float* ek = emb + k * CC;
            float a0 = 0.f, a1 = 0.f, a2 = 0.f, a3 = 0.f;
            #pragma unroll 8
            for (int c = 0; c < CC; ++c) {
                const float ev = ek[c];
                a0 = fmaf(xs[0][c], ev, a0);
                a1 = fmaf(xs[1][c], ev, a1);
                a2 = fmaf(xs[2][c], ev, a2);
                a3 = fmaf(xs[3][c], ev, a3);
            }
            const float eh = enh[k];
            const float key0 = eh - a0;
            if (key0 < bv[0] || (key0 == bv[0] && k < bi[0])) { bv[0] = key0; bi[0] = k; }
            const float key1 = eh - a1;
            if (key1 < bv[1] || (key1 == bv[1] && k < bi[1])) { bv[1] = key1; bi[1] = k; }
            const float key2 = eh - a2;
            if (key2 < bv[2] || (key2 == bv[2] && k < bi[2])) { bv[2] = key2; bi[2] = k; }
            const float key3 = eh - a3;
            if (key3 < bv[3] || (key3 == bv[3] && k < bi[3])) { bv[3] = key3; bi[3] = k; }
        }

        #pragma unroll
        for (int e = 0; e < RENT; ++e) {
            if (e >= nb) break;
            __syncthreads();
            rv[t] = bv[e]; ri[t] = bi[e];
            __syncthreads();
            for (int s = 128; s > 0; s >>= 1) {
                if (t < s) {
                    float ov = rv[t + s]; int oi = ri[t + s];
                    if (ov < rv[t] || (ov == rv[t] && oi < ri[t])) {
                        rv[t] = ov; ri[t] = oi;
                    }
                }
                __syncthreads();
            }
            const int code = ri[0];
            const int n    = ns[e];
            const int bb   = n >> 15;
            const int dhw  = n & (DHW - 1);
            if (t == 0) out[OUT_IDX + n] = (float)code;
            if (t < CC)
                out[OUT_Q + (size_t)bb * CC * DHW + (size_t)t * DHW + dhw] =
                    emb[code * CC + t];
        }
        __syncthreads();
    }
}

extern "C" void kernel_launch(void* const* d_in, const int* in_sizes, int n_in,
                              void* d_out, int out_size, void* d_ws, size_t ws_size,
                              hipStream_t stream) {
    const float* x   = (const float*)d_in[0];   // [4,128,32,32,32] fp32
    const float* emb = (const float*)d_in[1];   // [1024,128] fp32
    float* out = (float*)d_out;
    float* ws  = (float*)d_ws;

    float*  enh      = ws + WS_ENH;
    float*  loss_acc = ws + WS_LOSS;
    int*    cnt      = (int*)(ws + WS_CNT);
    int*    list     = (int*)(ws + WS_LIST);
    half8*  embH     = (half8*)(ws + WS_EMBH);

    prep_kernel<<<64, 256, 0, stream>>>(emb, embH, enh, loss_acc, cnt, out);
    argmin_kernel<<<NN / 128, 256, 0, stream>>>(x, embH, enh, emb,
                                                cnt, list, out, loss_acc);
    rescue_kernel<<<512, 256, 0, stream>>>(x, emb, enh, cnt, list, loss_acc, out);
}